// Round 5
// baseline (2657.181 us; speedup 1.0000x reference)
//
#include <hip/hip_runtime.h>
#include <hip/hip_bf16.h>

#define TSEQ  200
#define BATCH 256
#define INDIM 32
#define HID   512
#define GATES 2048

typedef __bf16 bf16x8 __attribute__((ext_vector_type(8)));
typedef float  f32x4  __attribute__((ext_vector_type(4)));
typedef unsigned long long u64;

// ---- workspace layout (bytes) ----
static constexpr size_t OFF_PW_IH0 = 0;          // 2048*32*2  = 128 KB
static constexpr size_t OFF_PW_HH0 = 0x20000;    // 2048*512*2 = 2 MB
static constexpr size_t OFF_PW_IH1 = 0x220000;   // 2 MB
static constexpr size_t OFF_PW_HH1 = 0x420000;   // 2 MB
static constexpr size_t OFF_B0     = 0x620000;   // 8 KB
static constexpr size_t OFF_B1     = 0x622000;   // 8 KB
static constexpr size_t OFF_H1B0   = 0x624000;   // 256 KB packed bf16 h (A-frag order)
static constexpr size_t OFF_H1B1   = 0x664000;
static constexpr size_t OFF_H2B0   = 0x6A4000;
static constexpr size_t OFF_H2B1   = 0x6E4000;
static constexpr size_t OFF_CTR    = 0x724000;   // 8 per-group counters, 1 KB apart
static constexpr size_t OFF_H2P    = 0x726000;   // 512 KB fp32 (final h2)
static constexpr size_t ZERO_OFF   = OFF_H1B0;
static constexpr size_t ZERO_LEN   = OFF_H2P + 0x80000 - OFF_H1B0;

__device__ __forceinline__ float sigm(float v) { return 1.f / (1.f + __expf(-v)); }

__device__ __forceinline__ bf16x8 as_bf16x8(f32x4 v) {
    union { f32x4 f; bf16x8 b; } u; u.f = v; return u.b;
}

// Issue a coherent (L2-bypass, sc1) 16B load WITHOUT any compiler wait:
// raw clause member; caller must s_waitcnt before consuming.
#define ISSUE_SC1(dst, addr) \
    asm volatile("global_load_dwordx4 %0, %1, off sc1" : "=v"(dst) : "v"(addr))

// Single waitcnt tying 16 pending frag registers: MFMAs consuming the tied
// outputs are data-dependent on this asm -> cannot be scheduled above it.
#define WAITTIE16(a) asm volatile("s_waitcnt vmcnt(0)" : \
    "+v"(a[0]),"+v"(a[1]),"+v"(a[2]),"+v"(a[3]),"+v"(a[4]),"+v"(a[5]),"+v"(a[6]),"+v"(a[7]), \
    "+v"(a[8]),"+v"(a[9]),"+v"(a[10]),"+v"(a[11]),"+v"(a[12]),"+v"(a[13]),"+v"(a[14]),"+v"(a[15]))

#define STORE_SC1_X2(addr, val) \
    asm volatile("global_store_dwordx2 %0, %1, off sc1" :: "v"(addr), "v"(val) : "memory")
#define STORE_SC1_DW(addr, val) \
    asm volatile("global_store_dword %0, %1, off sc1" :: "v"(addr), "v"(val) : "memory")

// Pack weight matrix W[2048][K] (fp32, row-major) into MFMA B-fragment order (bf16).
// frag[( (bn*8 + ty*2 + half)*KT + kt )*64 + lane][j];
// gate row g = ty*512 + bn*32 + half*16 + (lane&15); col k = kt*32 + (lane>>4)*8 + j.
__global__ void pack_w(const float* __restrict__ W, __bf16* __restrict__ out, int ktlog2)
{
    int tid = blockIdx.x * 256 + threadIdx.x;
    int K = 32 << ktlog2;
    int j    = tid & 7;
    int lane = (tid >> 3) & 63;
    int rest = tid >> 9;
    int kt   = rest & ((1 << ktlog2) - 1);
    int r2   = rest >> ktlog2;
    int lnt  = r2 & 7;
    int bn   = r2 >> 3;
    int type = lnt >> 1, half = lnt & 1;
    int g    = type * 512 + bn * 32 + half * 16 + (lane & 15);
    int kcol = kt * 32 + (lane >> 4) * 8 + j;
    out[tid] = (__bf16)W[g * K + kcol];
}

__global__ void bias_comb(const float* __restrict__ a0, const float* __restrict__ a1,
                          const float* __restrict__ a2, const float* __restrict__ a3,
                          float* __restrict__ o0, float* __restrict__ o1)
{
    int tid = blockIdx.x * 256 + threadIdx.x;
    if (tid < GATES) { o0[tid] = a0[tid] + a1[tid]; o1[tid] = a2[tid] + a3[tid]; }
}

// Persistent pipelined 2-layer LSTM.
// Grid: 256 blocks x 256 threads (4 waves). Blocks 0..127 layer0, 128..255 layer1.
// Block: 32 batches (mtp = lb>>4) x 32 hidden (bn = lb&15) x 4 gate types.
// layer0 wave = (kh, half): kh = K-half of W_hh0. layer1 wave = (kh, half):
// kh selects input (h1 vs h2), full K each. kh=1 waves dump partial gate sums to
// LDS; kh=0 waves reduce, hold c in registers, write h (sc1 asm stores).
// A-frags cross XCDs via one back-to-back sc1 load clause + single waitcnt.
__global__ __launch_bounds__(256, 1) void lstm_persist(const float* __restrict__ x,
                                                       const float* __restrict__ wfc,
                                                       const float* __restrict__ bfc,
                                                       char* __restrict__ ws,
                                                       float* __restrict__ out)
{
    const int layer = blockIdx.x >> 7;
    const int lb    = blockIdx.x & 127;
    const int mtp   = lb >> 4;            // batch group: [mtp*32, +32)
    const int bn    = lb & 15;            // hidden tile: [bn*32, +32)
    const int wid   = threadIdx.x >> 6;
    const int half  = wid & 1;
    const int kh    = wid >> 1;
    const int lane  = threadIdx.x & 63;
    const int q     = lane >> 4;
    const int c16   = lane & 15;
    unsigned* ctr   = (unsigned*)(ws + OFF_CTR) + (size_t)mtp * 256;

    __shared__ float  red[2][64][33];     // padded: bank = (lane+i)%32, conflict-free
    __shared__ __bf16 htr[1024];          // h transpose staging (kh0 waves only)

    const float* bias = (const float*)(ws + (layer ? OFF_B1 : OFF_B0));
    const int hidx = bn * 32 + half * 16 + c16;     // C/D col = lane&15
    const float bi  = bias[hidx];
    const float bff = bias[512 + hidx];
    const float bg  = bias[1024 + hidx];
    const float bo  = bias[1536 + hidx];

    const bf16x8* __restrict__ pBx = (const bf16x8*)(ws + OFF_PW_IH0);
    const bf16x8* __restrict__ pBh = (const bf16x8*)(ws + OFF_PW_HH0);
    const bf16x8* __restrict__ pB1 = (const bf16x8*)(ws + OFF_PW_IH1);
    const bf16x8* __restrict__ pB2 = (const bf16x8*)(ws + OFF_PW_HH1);
    float* __restrict__ h2p = (float*)(ws + OFF_H2P);

    float creg[8] = {0.f,0.f,0.f,0.f,0.f,0.f,0.f,0.f};   // c state (kh0 waves)

    for (int k = 0; k <= TSEQ; ++k) {
        const bool active = layer ? (k >= 1) : (k < TSEQ);
        if (active) {
            const int t  = k - layer;
            const int rd = (k + 1) & 1;
            const int wr = k & 1;
            f32x4 acc[2][4] = {};

            if (layer == 0) {
                const bf16x8* __restrict__ pA =
                    (const bf16x8*)(ws + (rd ? OFF_H1B1 : OFF_H1B0));
                f32x4 af[16];
                // one clause: 16 sc1 loads back-to-back, no intermediate waits
                #pragma unroll
                for (int j = 0; j < 8; ++j) {
                    ISSUE_SC1(af[j],     &pA[((mtp * 2 + 0) * 16 + kh * 8 + j) * 64 + lane]);
                    ISSUE_SC1(af[8 + j], &pA[((mtp * 2 + 1) * 16 + kh * 8 + j) * 64 + lane]);
                }
                if (kh == 0) {
                    // x projection (K=32); overlaps the in-flight A clause
                    #pragma unroll
                    for (int m = 0; m < 2; ++m) {
                        const int b = (mtp * 2 + m) * 16 + c16;
                        const float* xp = x + ((size_t)b * TSEQ + t) * INDIM + q * 8;
                        float4 xlo = *(const float4*)xp;
                        float4 xhi = *(const float4*)(xp + 4);
                        bf16x8 ax;
                        ax[0] = (__bf16)xlo.x; ax[1] = (__bf16)xlo.y;
                        ax[2] = (__bf16)xlo.z; ax[3] = (__bf16)xlo.w;
                        ax[4] = (__bf16)xhi.x; ax[5] = (__bf16)xhi.y;
                        ax[6] = (__bf16)xhi.z; ax[7] = (__bf16)xhi.w;
                        #pragma unroll
                        for (int ty = 0; ty < 4; ++ty) {
                            bf16x8 bf = pBx[(bn * 8 + ty * 2 + half) * 64 + lane];
                            acc[m][ty] = __builtin_amdgcn_mfma_f32_16x16x32_bf16(ax, bf, acc[m][ty], 0, 0, 0);
                        }
                    }
                }
                WAITTIE16(af);            // single L3 latency exposure
                #pragma unroll
                for (int j = 0; j < 8; ++j) {
                    #pragma unroll
                    for (int ty = 0; ty < 4; ++ty) {
                        bf16x8 bf = pBh[((bn * 8 + ty * 2 + half) * 16 + kh * 8 + j) * 64 + lane];
                        acc[0][ty] = __builtin_amdgcn_mfma_f32_16x16x32_bf16(as_bf16x8(af[j]),     bf, acc[0][ty], 0, 0, 0);
                        acc[1][ty] = __builtin_amdgcn_mfma_f32_16x16x32_bf16(as_bf16x8(af[8 + j]), bf, acc[1][ty], 0, 0, 0);
                    }
                }
            } else {
                const bf16x8* __restrict__ pA =
                    (const bf16x8*)(ws + (kh ? (rd ? OFF_H2B1 : OFF_H2B0)
                                             : (rd ? OFF_H1B1 : OFF_H1B0)));
                const bf16x8* __restrict__ pW = kh ? pB2 : pB1;
                f32x4 a0[16], a1[16];
                #pragma unroll
                for (int j = 0; j < 8; ++j) {
                    ISSUE_SC1(a0[j],     &pA[((mtp * 2 + 0) * 16 + j) * 64 + lane]);
                    ISSUE_SC1(a0[8 + j], &pA[((mtp * 2 + 1) * 16 + j) * 64 + lane]);
                }
                #pragma unroll
                for (int j = 0; j < 8; ++j) {
                    ISSUE_SC1(a1[j],     &pA[((mtp * 2 + 0) * 16 + 8 + j) * 64 + lane]);
                    ISSUE_SC1(a1[8 + j], &pA[((mtp * 2 + 1) * 16 + 8 + j) * 64 + lane]);
                }
                WAITTIE16(a0);            // drains whole clause (in-order retire)
                #pragma unroll
                for (int j = 0; j < 8; ++j) {
                    #pragma unroll
                    for (int ty = 0; ty < 4; ++ty) {
                        bf16x8 bf = pW[((bn * 8 + ty * 2 + half) * 16 + j) * 64 + lane];
                        acc[0][ty] = __builtin_amdgcn_mfma_f32_16x16x32_bf16(as_bf16x8(a0[j]),     bf, acc[0][ty], 0, 0, 0);
                        acc[1][ty] = __builtin_amdgcn_mfma_f32_16x16x32_bf16(as_bf16x8(a0[8 + j]), bf, acc[1][ty], 0, 0, 0);
                    }
                }
                WAITTIE16(a1);            // free by now
                #pragma unroll
                for (int j = 0; j < 8; ++j) {
                    #pragma unroll
                    for (int ty = 0; ty < 4; ++ty) {
                        bf16x8 bf = pW[((bn * 8 + ty * 2 + half) * 16 + 8 + j) * 64 + lane];
                        acc[0][ty] = __builtin_amdgcn_mfma_f32_16x16x32_bf16(as_bf16x8(a1[j]),     bf, acc[0][ty], 0, 0, 0);
                        acc[1][ty] = __builtin_amdgcn_mfma_f32_16x16x32_bf16(as_bf16x8(a1[8 + j]), bf, acc[1][ty], 0, 0, 0);
                    }
                }
            }

            // ---- cross-wave K reduction ----
            if (kh == 1) {
                #pragma unroll
                for (int m = 0; m < 2; ++m)
                    #pragma unroll
                    for (int ty = 0; ty < 4; ++ty)
                        #pragma unroll
                        for (int r = 0; r < 4; ++r)
                            red[half][lane][m * 16 + ty * 4 + r] = acc[m][ty][r];
            }
            __syncthreads();

            if (kh == 0) {
                __bf16* __restrict__ hout = (__bf16*)(ws + (layer ? (wr ? OFF_H2B1 : OFF_H2B0)
                                                                  : (wr ? OFF_H1B1 : OFF_H1B0)));
                #pragma unroll
                for (int m = 0; m < 2; ++m) {
                    #pragma unroll
                    for (int r = 0; r < 4; ++r) {
                        float pi = acc[m][0][r] + red[half][lane][m * 16 + r]      + bi;
                        float pf = acc[m][1][r] + red[half][lane][m * 16 + 4 + r]  + bff;
                        float pg = acc[m][2][r] + red[half][lane][m * 16 + 8 + r]  + bg;
                        float po = acc[m][3][r] + red[half][lane][m * 16 + 12 + r] + bo;
                        float cn = sigm(pf) * creg[m * 4 + r] + sigm(pi) * tanhf(pg);
                        float hn = sigm(po) * tanhf(cn);
                        creg[m * 4 + r] = cn;
                        htr[half * 512 + (m * 16 + q * 4 + r) * 16 + c16] = (__bf16)hn;
                        if (layer == 1 && k == TSEQ) {
                            const int b = (mtp * 2 + m) * 16 + q * 4 + r;
                            STORE_SC1_DW(&h2p[b * HID + hidx], hn);
                        }
                    }
                }
                // wave-local LDS transpose -> coalesced 8B coherent h stores
                const int bt   = lane >> 5;
                const int qa1  = (lane >> 4) & 1;
                const int b15r = lane & 15;
                const u64* lp = (const u64*)&htr[half * 512 + (bt * 16 + b15r) * 16 + qa1 * 8];
                u64 v0 = lp[0], v1 = lp[1];
                const int f = (((mtp * 2 + bt) * 16) + bn) * 64 + (half * 2 + qa1) * 16 + b15r;
                u64* gp = (u64*)hout + (size_t)f * 2;
                STORE_SC1_X2(gp,     v0);
                STORE_SC1_X2(gp + 1, v1);
            }
        }

        // ---- per-group barrier (32 blocks, own cache line, no invalidation) ----
        asm volatile("s_waitcnt vmcnt(0)" ::: "memory");
        __syncthreads();
        if (threadIdx.x == 0) {
            __hip_atomic_fetch_add(ctr, 1u, __ATOMIC_RELAXED, __HIP_MEMORY_SCOPE_AGENT);
            const unsigned tgt = 32u * (unsigned)(k + 1);
            while (__hip_atomic_load(ctr, __ATOMIC_RELAXED, __HIP_MEMORY_SCOPE_AGENT) < tgt)
                __builtin_amdgcn_s_sleep(1);
        }
        __syncthreads();
    }

    // ---- fused FC epilogue: one batch per block (group-local mapping) ----
    if (threadIdx.x < 64) {
        const int b = mtp * 32 + layer * 16 + bn;
        const float* h = h2p + b * HID;
        float hv[8];
        #pragma unroll
        for (int j = 0; j < 8; ++j)
            hv[j] = __hip_atomic_load(&h[lane * 8 + j], __ATOMIC_RELAXED, __HIP_MEMORY_SCOPE_AGENT);
        float y[7];
        #pragma unroll
        for (int o = 0; o < 7; ++o) {
            const float* wrow = wfc + o * HID;
            float s = 0.f;
            #pragma unroll
            for (int j = 0; j < 8; ++j) s += hv[j] * wrow[lane * 8 + j];
            #pragma unroll
            for (int off = 32; off >= 1; off >>= 1) s += __shfl_down(s, off);
            y[o] = s;
        }
        if (lane == 0) {
            out[b * 3 + 0] = sigm(y[0] + bfc[0]);
            out[b * 3 + 1] = sigm(y[1] + bfc[1]);
            out[b * 3 + 2] = sigm(y[2] + bfc[2]);
            float r0 = tanhf(y[3] + bfc[3]);
            float r1 = tanhf(y[4] + bfc[4]);
            float r2 = tanhf(y[5] + bfc[5]);
            float r3 = tanhf(y[6] + bfc[6]);
            float n = sqrtf(r0 * r0 + r1 * r1 + r2 * r2 + r3 * r3);
            n = fmaxf(n, 1e-12f);
            out[768 + b * 4 + 0] = r0 / n;
            out[768 + b * 4 + 1] = r1 / n;
            out[768 + b * 4 + 2] = r2 / n;
            out[768 + b * 4 + 3] = r3 / n;
        }
    }
}

extern "C" void kernel_launch(void* const* d_in, const int* in_sizes, int n_in,
                              void* d_out, int out_size, void* d_ws, size_t ws_size,
                              hipStream_t stream)
{
    const float* x    = (const float*)d_in[0];
    const float* wih0 = (const float*)d_in[1];
    const float* whh0 = (const float*)d_in[2];
    const float* bih0 = (const float*)d_in[3];
    const float* bhh0 = (const float*)d_in[4];
    const float* wih1 = (const float*)d_in[5];
    const float* whh1 = (const float*)d_in[6];
    const float* bih1 = (const float*)d_in[7];
    const float* bhh1 = (const float*)d_in[8];
    const float* wfc  = (const float*)d_in[9];
    const float* bfc  = (const float*)d_in[10];
    char* ws = (char*)d_ws;

    // zero h ping-pong buffers + barrier counters (+h2p page)
    hipMemsetAsync(ws + ZERO_OFF, 0, ZERO_LEN, stream);

    // prologue: pack weights into MFMA fragment order (bf16), combine biases
    pack_w<<<256,  256, 0, stream>>>(wih0, (__bf16*)(ws + OFF_PW_IH0), 0);
    pack_w<<<4096, 256, 0, stream>>>(whh0, (__bf16*)(ws + OFF_PW_HH0), 4);
    pack_w<<<4096, 256, 0, stream>>>(wih1, (__bf16*)(ws + OFF_PW_IH1), 4);
    pack_w<<<4096, 256, 0, stream>>>(whh1, (__bf16*)(ws + OFF_PW_HH1), 4);
    bias_comb<<<8, 256, 0, stream>>>(bih0, bhh0, bih1, bhh1,
                                     (float*)(ws + OFF_B0), (float*)(ws + OFF_B1));

    // one persistent kernel: 201 pipelined steps, per-group barriers, fused FC
    lstm_persist<<<256, 256, 0, stream>>>(x, wfc, bfc, ws, (float*)d_out);
}

// Round 7
// 1976.288 us; speedup vs baseline: 1.3445x; 1.3445x over previous
//
#include <hip/hip_runtime.h>
#include <hip/hip_bf16.h>

#define TSEQ  200
#define BATCH 256
#define INDIM 32
#define HID   512
#define GATES 2048

typedef __bf16 bf16x8 __attribute__((ext_vector_type(8)));
typedef float  f32x4  __attribute__((ext_vector_type(4)));
typedef unsigned long long u64;

// ---- workspace layout (bytes) ----
static constexpr size_t OFF_PW_IH0 = 0;          // 2048*32*2  = 128 KB
static constexpr size_t OFF_PW_HH0 = 0x20000;    // 2048*512*2 = 2 MB
static constexpr size_t OFF_PW_IH1 = 0x220000;   // 2 MB
static constexpr size_t OFF_PW_HH1 = 0x420000;   // 2 MB
static constexpr size_t OFF_B0     = 0x620000;   // 8 KB
static constexpr size_t OFF_B1     = 0x622000;   // 8 KB
static constexpr size_t OFF_H1B0   = 0x624000;   // 256 KB packed bf16 h (A-frag order)
static constexpr size_t OFF_H1B1   = 0x664000;
static constexpr size_t OFF_H2B0   = 0x6A4000;
static constexpr size_t OFF_H2B1   = 0x6E4000;
static constexpr size_t OFF_CTR    = 0x724000;   // 8 per-group counters, 1 KB apart
static constexpr size_t OFF_H2P    = 0x726000;   // 512 KB fp32 (final h2)
static constexpr size_t ZERO_OFF   = OFF_H1B0;
static constexpr size_t ZERO_LEN   = OFF_H2P + 0x80000 - OFF_H1B0;

__device__ __forceinline__ float sigm(float v) { return 1.f / (1.f + __expf(-v)); }

__device__ __forceinline__ bf16x8 as_bf16x8(f32x4 v) {
    union { f32x4 f; bf16x8 b; } u; u.f = v; return u.b;
}

// Coherent (L2-bypassing, sc1) 16-byte fragment load as 2x relaxed agent atomics.
// Relaxed atomics need no waitcnt between themselves -> compiler clusters them.
__device__ __forceinline__ bf16x8 load_frag_coh(const bf16x8* p) {
    const u64* q = (const u64*)p;
    union { u64 u[2]; bf16x8 v; } cv;
    cv.u[0] = __hip_atomic_load(q,     __ATOMIC_RELAXED, __HIP_MEMORY_SCOPE_AGENT);
    cv.u[1] = __hip_atomic_load(q + 1, __ATOMIC_RELAXED, __HIP_MEMORY_SCOPE_AGENT);
    return cv.v;
}

// Pack weight matrix W[2048][K] (fp32, row-major) into MFMA B-fragment order (bf16).
// frag[( (bn*8 + ty*2 + half)*KT + kt )*64 + lane][j];
// gate row g = ty*512 + bn*32 + half*16 + (lane&15); col k = kt*32 + (lane>>4)*8 + j.
__global__ void pack_w(const float* __restrict__ W, __bf16* __restrict__ out, int ktlog2)
{
    int tid = blockIdx.x * 256 + threadIdx.x;
    int K = 32 << ktlog2;
    int j    = tid & 7;
    int lane = (tid >> 3) & 63;
    int rest = tid >> 9;
    int kt   = rest & ((1 << ktlog2) - 1);
    int r2   = rest >> ktlog2;
    int lnt  = r2 & 7;
    int bn   = r2 >> 3;
    int type = lnt >> 1, half = lnt & 1;
    int g    = type * 512 + bn * 32 + half * 16 + (lane & 15);
    int kcol = kt * 32 + (lane >> 4) * 8 + j;
    out[tid] = (__bf16)W[g * K + kcol];
}

__global__ void bias_comb(const float* __restrict__ a0, const float* __restrict__ a1,
                          const float* __restrict__ a2, const float* __restrict__ a3,
                          float* __restrict__ o0, float* __restrict__ o1)
{
    int tid = blockIdx.x * 256 + threadIdx.x;
    if (tid < GATES) { o0[tid] = a0[tid] + a1[tid]; o1[tid] = a2[tid] + a3[tid]; }
}

// Persistent pipelined 2-layer LSTM, weights register-resident.
// Grid: 256 blocks x 256 threads (4 waves). Blocks 0..127 layer0, 128..255 layer1.
// Block: 32 batches (mtp = lb>>4) x 32 hidden (bn = lb&15) x 4 gate types.
// Wave = (kh, half). Each wave preloads its ENTIRE weight slice into VGPRs
// (layer1: 64 frags = 256 VGPRs; layer0: 36 frags) before the time loop --
// the per-step K-loop then touches no weight memory at all.
// kh=1 waves dump partial gate sums to LDS; kh=0 waves reduce, hold c in
// registers, write h (sc1). Per-group (32-block) barriers, no cache inval.
__global__ __launch_bounds__(256, 1) void lstm_persist(const float* __restrict__ x,
                                                       const float* __restrict__ wfc,
                                                       const float* __restrict__ bfc,
                                                       char* __restrict__ ws,
                                                       float* __restrict__ out)
{
    const int layer = blockIdx.x >> 7;
    const int lb    = blockIdx.x & 127;
    const int mtp   = lb >> 4;            // batch group: [mtp*32, +32)
    const int bn    = lb & 15;            // hidden tile: [bn*32, +32)
    const int wid   = threadIdx.x >> 6;
    const int half  = wid & 1;
    const int kh    = wid >> 1;
    const int lane  = threadIdx.x & 63;
    const int q     = lane >> 4;
    const int c16   = lane & 15;
    unsigned* ctr   = (unsigned*)(ws + OFF_CTR) + (size_t)mtp * 256;

    __shared__ float  red[2][64][33];     // padded: conflict-free cross-wave reduction
    __shared__ __bf16 htr[1024];          // h transpose staging (kh0 waves only)

    const float* bias = (const float*)(ws + (layer ? OFF_B1 : OFF_B0));
    const int hidx = bn * 32 + half * 16 + c16;     // C/D col = lane&15
    const float bi  = bias[hidx];
    const float bff = bias[512 + hidx];
    const float bg  = bias[1024 + hidx];
    const float bo  = bias[1536 + hidx];

    const bf16x8* __restrict__ pBx = (const bf16x8*)(ws + OFF_PW_IH0);
    const bf16x8* __restrict__ pBh = (const bf16x8*)(ws + OFF_PW_HH0);
    const bf16x8* __restrict__ pB1 = (const bf16x8*)(ws + OFF_PW_IH1);
    const bf16x8* __restrict__ pB2 = (const bf16x8*)(ws + OFF_PW_HH1);
    float* __restrict__ h2p = (float*)(ws + OFF_H2P);

    // ---- preload weight slice into registers (once; written by prior dispatch) ----
    f32x4 Bw[64];                         // layer1: [kt(16)][ty(4)]; layer0: [kt(8)][ty(4)]
    f32x4 Bx[4];                          // layer0 x-projection frags
    if (layer == 0) {
        #pragma unroll
        for (int j = 0; j < 8; ++j)
            #pragma unroll
            for (int ty = 0; ty < 4; ++ty)
                Bw[j * 4 + ty] = *(const f32x4*)&pBh[((bn * 8 + ty * 2 + half) * 16 + kh * 8 + j) * 64 + lane];
        #pragma unroll
        for (int ty = 0; ty < 4; ++ty)
            Bx[ty] = *(const f32x4*)&pBx[(bn * 8 + ty * 2 + half) * 64 + lane];
    } else {
        const bf16x8* __restrict__ pW = kh ? pB2 : pB1;
        #pragma unroll
        for (int j = 0; j < 16; ++j)
            #pragma unroll
            for (int ty = 0; ty < 4; ++ty)
                Bw[j * 4 + ty] = *(const f32x4*)&pW[((bn * 8 + ty * 2 + half) * 16 + j) * 64 + lane];
    }

    float creg[8] = {0.f,0.f,0.f,0.f,0.f,0.f,0.f,0.f};   // c state (kh0 waves)

    // 16 A-frag loads (2 m-tiles x 8 kt); relaxed atomics, compiler-clustered
    auto loadA = [&](bf16x8* dst, const bf16x8* pA, int kt0) {
        #pragma unroll
        for (int j = 0; j < 8; ++j) {
            dst[j]     = load_frag_coh(&pA[((mtp * 2 + 0) * 16 + kt0 + j) * 64 + lane]);
            dst[8 + j] = load_frag_coh(&pA[((mtp * 2 + 1) * 16 + kt0 + j) * 64 + lane]);
        }
    };

    for (int k = 0; k <= TSEQ; ++k) {
        const bool active = layer ? (k >= 1) : (k < TSEQ);
        if (active) {
            const int t  = k - layer;
            const int rd = (k + 1) & 1;
            const int wr = k & 1;
            f32x4 acc[2][4] = {};

            if (layer == 0) {
                const bf16x8* __restrict__ pA =
                    (const bf16x8*)(ws + (rd ? OFF_H1B1 : OFF_H1B0));
                bf16x8 af[16];
                loadA(af, pA, kh * 8);
                if (kh == 0) {
                    // x projection (K=32); weights already in registers
                    #pragma unroll
                    for (int m = 0; m < 2; ++m) {
                        const int b = (mtp * 2 + m) * 16 + c16;
                        const float* xp = x + ((size_t)b * TSEQ + t) * INDIM + q * 8;
                        float4 xlo = *(const float4*)xp;
                        float4 xhi = *(const float4*)(xp + 4);
                        bf16x8 ax;
                        ax[0] = (__bf16)xlo.x; ax[1] = (__bf16)xlo.y;
                        ax[2] = (__bf16)xlo.z; ax[3] = (__bf16)xlo.w;
                        ax[4] = (__bf16)xhi.x; ax[5] = (__bf16)xhi.y;
                        ax[6] = (__bf16)xhi.z; ax[7] = (__bf16)xhi.w;
                        #pragma unroll
                        for (int ty = 0; ty < 4; ++ty)
                            acc[m][ty] = __builtin_amdgcn_mfma_f32_16x16x32_bf16(ax, as_bf16x8(Bx[ty]), acc[m][ty], 0, 0, 0);
                    }
                }
                #pragma unroll
                for (int j = 0; j < 8; ++j) {
                    #pragma unroll
                    for (int ty = 0; ty < 4; ++ty) {
                        acc[0][ty] = __builtin_amdgcn_mfma_f32_16x16x32_bf16(af[j],     as_bf16x8(Bw[j * 4 + ty]), acc[0][ty], 0, 0, 0);
                        acc[1][ty] = __builtin_amdgcn_mfma_f32_16x16x32_bf16(af[8 + j], as_bf16x8(Bw[j * 4 + ty]), acc[1][ty], 0, 0, 0);
                    }
                }
            } else {
                const bf16x8* __restrict__ pA =
                    (const bf16x8*)(ws + (kh ? (rd ? OFF_H2B1 : OFF_H2B0)
                                             : (rd ? OFF_H1B1 : OFF_H1B0)));
                bf16x8 a0[16], a1[16];
                loadA(a0, pA, 0);
                loadA(a1, pA, 8);
                #pragma unroll
                for (int j = 0; j < 8; ++j) {
                    #pragma unroll
                    for (int ty = 0; ty < 4; ++ty) {
                        acc[0][ty] = __builtin_amdgcn_mfma_f32_16x16x32_bf16(a0[j],     as_bf16x8(Bw[j * 4 + ty]), acc[0][ty], 0, 0, 0);
                        acc[1][ty] = __builtin_amdgcn_mfma_f32_16x16x32_bf16(a0[8 + j], as_bf16x8(Bw[j * 4 + ty]), acc[1][ty], 0, 0, 0);
                    }
                }
                #pragma unroll
                for (int j = 0; j < 8; ++j) {
                    #pragma unroll
                    for (int ty = 0; ty < 4; ++ty) {
                        acc[0][ty] = __builtin_amdgcn_mfma_f32_16x16x32_bf16(a1[j],     as_bf16x8(Bw[(8 + j) * 4 + ty]), acc[0][ty], 0, 0, 0);
                        acc[1][ty] = __builtin_amdgcn_mfma_f32_16x16x32_bf16(a1[8 + j], as_bf16x8(Bw[(8 + j) * 4 + ty]), acc[1][ty], 0, 0, 0);
                    }
                }
            }

            // ---- cross-wave K reduction ----
            if (kh == 1) {
                #pragma unroll
                for (int m = 0; m < 2; ++m)
                    #pragma unroll
                    for (int ty = 0; ty < 4; ++ty)
                        #pragma unroll
                        for (int r = 0; r < 4; ++r)
                            red[half][lane][m * 16 + ty * 4 + r] = acc[m][ty][r];
            }
            __syncthreads();

            if (kh == 0) {
                __bf16* __restrict__ hout = (__bf16*)(ws + (layer ? (wr ? OFF_H2B1 : OFF_H2B0)
                                                                  : (wr ? OFF_H1B1 : OFF_H1B0)));
                #pragma unroll
                for (int m = 0; m < 2; ++m) {
                    #pragma unroll
                    for (int r = 0; r < 4; ++r) {
                        float pi = acc[m][0][r] + red[half][lane][m * 16 + r]      + bi;
                        float pf = acc[m][1][r] + red[half][lane][m * 16 + 4 + r]  + bff;
                        float pg = acc[m][2][r] + red[half][lane][m * 16 + 8 + r]  + bg;
                        float po = acc[m][3][r] + red[half][lane][m * 16 + 12 + r] + bo;
                        float cn = sigm(pf) * creg[m * 4 + r] + sigm(pi) * tanhf(pg);
                        float hn = sigm(po) * tanhf(cn);
                        creg[m * 4 + r] = cn;
                        htr[half * 512 + (m * 16 + q * 4 + r) * 16 + c16] = (__bf16)hn;
                        if (layer == 1 && k == TSEQ) {
                            const int b = (mtp * 2 + m) * 16 + q * 4 + r;
                            __hip_atomic_store(&h2p[b * HID + hidx], hn,
                                               __ATOMIC_RELAXED, __HIP_MEMORY_SCOPE_AGENT);
                        }
                    }
                }
                // wave-local LDS transpose -> coalesced 8B coherent h stores
                const int bt   = lane >> 5;
                const int qa1  = (lane >> 4) & 1;
                const int b15r = lane & 15;
                const u64* lp = (const u64*)&htr[half * 512 + (bt * 16 + b15r) * 16 + qa1 * 8];
                u64 v0 = lp[0], v1 = lp[1];
                const int f = (((mtp * 2 + bt) * 16) + bn) * 64 + (half * 2 + qa1) * 16 + b15r;
                u64* gp = (u64*)hout + (size_t)f * 2;
                __hip_atomic_store(gp,     v0, __ATOMIC_RELAXED, __HIP_MEMORY_SCOPE_AGENT);
                __hip_atomic_store(gp + 1, v1, __ATOMIC_RELAXED, __HIP_MEMORY_SCOPE_AGENT);
            }
        }

        // ---- per-group barrier (32 blocks, own cache line, no invalidation) ----
        asm volatile("s_waitcnt vmcnt(0)" ::: "memory");
        __syncthreads();
        if (threadIdx.x == 0) {
            __hip_atomic_fetch_add(ctr, 1u, __ATOMIC_RELAXED, __HIP_MEMORY_SCOPE_AGENT);
            const unsigned tgt = 32u * (unsigned)(k + 1);
            while (__hip_atomic_load(ctr, __ATOMIC_RELAXED, __HIP_MEMORY_SCOPE_AGENT) < tgt)
                __builtin_amdgcn_s_sleep(1);
        }
        __syncthreads();
    }

    // ---- fused FC epilogue: one batch per block (group-local mapping) ----
    if (threadIdx.x < 64) {
        const int b = mtp * 32 + layer * 16 + bn;
        const float* h = h2p + b * HID;
        float hv[8];
        #pragma unroll
        for (int j = 0; j < 8; ++j)
            hv[j] = __hip_atomic_load(&h[lane * 8 + j], __ATOMIC_RELAXED, __HIP_MEMORY_SCOPE_AGENT);
        float y[7];
        #pragma unroll
        for (int o = 0; o < 7; ++o) {
            const float* wrow = wfc + o * HID;
            float s = 0.f;
            #pragma unroll
            for (int j = 0; j < 8; ++j) s += hv[j] * wrow[lane * 8 + j];
            #pragma unroll
            for (int off = 32; off >= 1; off >>= 1) s += __shfl_down(s, off);
            y[o] = s;
        }
        if (lane == 0) {
            out[b * 3 + 0] = sigm(y[0] + bfc[0]);
            out[b * 3 + 1] = sigm(y[1] + bfc[1]);
            out[b * 3 + 2] = sigm(y[2] + bfc[2]);
            float r0 = tanhf(y[3] + bfc[3]);
            float r1 = tanhf(y[4] + bfc[4]);
            float r2 = tanhf(y[5] + bfc[5]);
            float r3 = tanhf(y[6] + bfc[6]);
            float n = sqrtf(r0 * r0 + r1 * r1 + r2 * r2 + r3 * r3);
            n = fmaxf(n, 1e-12f);
            out[768 + b * 4 + 0] = r0 / n;
            out[768 + b * 4 + 1] = r1 / n;
            out[768 + b * 4 + 2] = r2 / n;
            out[768 + b * 4 + 3] = r3 / n;
        }
    }
}

extern "C" void kernel_launch(void* const* d_in, const int* in_sizes, int n_in,
                              void* d_out, int out_size, void* d_ws, size_t ws_size,
                              hipStream_t stream)
{
    const float* x    = (const float*)d_in[0];
    const float* wih0 = (const float*)d_in[1];
    const float* whh0 = (const float*)d_in[2];
    const float* bih0 = (const float*)d_in[3];
    const float* bhh0 = (const float*)d_in[4];
    const float* wih1 = (const float*)d_in[5];
    const float* whh1 = (const float*)d_in[6];
    const float* bih1 = (const float*)d_in[7];
    const float* bhh1 = (const float*)d_in[8];
    const float* wfc  = (const float*)d_in[9];
    const float* bfc  = (const float*)d_in[10];
    char* ws = (char*)d_ws;

    // zero h ping-pong buffers + barrier counters + h2p
    hipMemsetAsync(ws + ZERO_OFF, 0, ZERO_LEN, stream);

    // prologue: pack weights into MFMA fragment order (bf16), combine biases
    pack_w<<<256,  256, 0, stream>>>(wih0, (__bf16*)(ws + OFF_PW_IH0), 0);
    pack_w<<<4096, 256, 0, stream>>>(whh0, (__bf16*)(ws + OFF_PW_HH0), 4);
    pack_w<<<4096, 256, 0, stream>>>(wih1, (__bf16*)(ws + OFF_PW_IH1), 4);
    pack_w<<<4096, 256, 0, stream>>>(whh1, (__bf16*)(ws + OFF_PW_HH1), 4);
    bias_comb<<<8, 256, 0, stream>>>(bih0, bhh0, bih1, bhh1,
                                     (float*)(ws + OFF_B0), (float*)(ws + OFF_B1));

    // one persistent kernel: weights register-resident, 201 pipelined steps
    lstm_persist<<<256, 256, 0, stream>>>(x, wfc, bfc, ws, (float*)d_out);
}